// Round 8
// baseline (254.821 us; speedup 1.0000x reference)
//
#include <hip/hip_runtime.h>

#define N_NODES 100000
#define N_EDGES 1000000
#define D_IN    256
#define D_OUT   64

// 16-node buckets: MFMA aggregation out[16n x 64d] = P[16 x E] @ H[E x 64d]
// (round 7, verified). Round 8: bin is a zero-LDS direct-append PROLOGUE in
// every gemm block (5 edges/thread): global atomicAdd-return reserves the
// slot, scatter-store fills it. ~160 same-bucket RMWs serialize per counter
// (~3-6 us machine-wide, parallel across 6250 counters); no histogram, no
// barriers, no dedicated bin blocks, one less dispatch gap.
#define BKT_SHIFT   4
#define NODES_PER_BKT 16
#define N_BKT       6250
#define BKT_CAP     256            // mean 160, sigma ~12.6 -> +7.6 sigma
#define GEMM_BLOCKS 782            // 3128 waves, 2 tiles/wave, 6250 tiles exact
#define NUM_TILES   6250           // 100000 / 16 exactly
#define EDGES_PER_BLK 1280         // 782 * 1280 = 1,000,960 >= 1e6
#define AGG_BLOCKS  782            // 8 wave-buckets/block -> 6256 >= 6250

typedef __attribute__((ext_vector_type(8))) short short8;
typedef __attribute__((ext_vector_type(4))) float f32x4;
typedef __attribute__((ext_vector_type(4))) unsigned short u16x4;

__device__ __forceinline__ unsigned short f2bf(float f) {
    unsigned int u = __float_as_uint(f);
    u = (u + 0x7fffu + ((u >> 16) & 1u)) >> 16;
    return (unsigned short)u;
}

// MFMA + store for one 16-row tile; B read from LDS per use (keeps VGPRs for
// the A-load pipeline). wT pad = 272 shorts (544 B = 8 banks offset/row ->
// 4-way b128 aliasing instead of 8-way at 264).
__device__ __forceinline__ void mfma_store_tile(
    const short8 afrag[8], const unsigned short wT[64][272],
    unsigned short* __restrict__ hiddenBf, int r0, int n16, int quad)
{
    f32x4 acc[4] = {{0.f,0.f,0.f,0.f},{0.f,0.f,0.f,0.f},
                    {0.f,0.f,0.f,0.f},{0.f,0.f,0.f,0.f}};
#pragma unroll
    for (int ct = 0; ct < 4; ++ct) {
#pragma unroll
        for (int kk = 0; kk < 8; ++kk) {
            short8 b = *(const short8*)&wT[ct * 16 + n16][kk * 32 + quad * 8];
            acc[ct] = __builtin_amdgcn_mfma_f32_16x16x32_bf16(
                afrag[kk], b, acc[ct], 0, 0, 0);
        }
    }
    // C/D layout: col = lane&15, row = quad*4 + reg  [m89-verified]
#pragma unroll
    for (int ct = 0; ct < 4; ++ct)
#pragma unroll
        for (int reg = 0; reg < 4; ++reg)
            hiddenBf[(size_t)(r0 + quad * 4 + reg) * D_OUT + ct * 16 + n16]
                = f2bf(acc[ct][reg]);
}

// ---------------------------------------------------------------------------
// Fused GEMM + direct-append bin. Bin prologue per block: 5 edges/thread,
// batched loads; per edge one global atomicAdd-return + one 8-B scatter
// store (payload: node_local<<17 | col, adj split hi/lo bf16). The atomic
// latencies overlap the subsequent wT staging + x-tile load pipeline.
// LDS = wT only (34.8 KB) -> 4 blocks/CU.
// ---------------------------------------------------------------------------
__global__ __launch_bounds__(256, 2) void gemm_bin_kernel(
    const float* __restrict__ x, const float* __restrict__ w,
    unsigned short* __restrict__ hiddenBf,
    const int* __restrict__ row, const int* __restrict__ col,
    const float* __restrict__ adj, int* __restrict__ gCursor,
    int2* __restrict__ edges)
{
    const int t = threadIdx.x;

    // ----- bin prologue (no LDS, no barriers) -----
    {
        const int e0 = blockIdx.x * EDGES_PER_BLK;
        int rr[5]; int cc[5]; float vv[5];
#pragma unroll
        for (int u = 0; u < 5; ++u) {
            int e = e0 + u * 256 + t;
            rr[u] = (e < N_EDGES) ? row[e] : -1;
        }
#pragma unroll
        for (int u = 0; u < 5; ++u) {
            int e = e0 + u * 256 + t;
            if (rr[u] >= 0) { cc[u] = col[e]; vv[u] = adj[e]; }
            else            { cc[u] = 0;      vv[u] = 0.f;    }
        }
#pragma unroll
        for (int u = 0; u < 5; ++u) {
            int r = rr[u];
            if (r >= 0) {
                int b = r >> BKT_SHIFT;
                int off = atomicAdd(&gCursor[b], 1);
                if (off < BKT_CAP) {  // capacity guard (never trips)
                    unsigned hi = f2bf(vv[u]);
                    float hif   = __uint_as_float(hi << 16);
                    unsigned lo = f2bf(vv[u] - hif);
                    edges[b * BKT_CAP + off] =
                        make_int2(((r & (NODES_PER_BKT - 1)) << 17) | cc[u],
                                  (int)((hi << 16) | lo));
                }
            }
        }
    }

    // ----- gemm path (unchanged) -----
    __shared__ unsigned short wT[64][272];

    for (int i = 0; i < 64; ++i) {
        int idx = t + i * 256;
        int k = idx >> 6, n = idx & 63;
        wT[n][k] = f2bf(w[idx]);
    }
    __syncthreads();

    const int lane = t & 63;
    const int wid  = t >> 6;
    const int n16  = lane & 15;
    const int quad = lane >> 4;

    const int waveGid = blockIdx.x * 4 + wid;
    const int t0 = waveGid * 2;
    if (t0 >= NUM_TILES) return;

    float4 lo[8], hi[8];
    short8 afrag[8];

    // prologue: issue all 16 loads of tile t0
    {
        const float* xrow = x + (size_t)(t0 * 16 + n16) * D_IN + quad * 8;
#pragma unroll
        for (int kk = 0; kk < 8; ++kk) {
            lo[kk] = *(const float4*)(xrow + kk * 32);
            hi[kk] = *(const float4*)(xrow + kk * 32 + 4);
        }
    }
#pragma unroll
    for (int kk = 0; kk < 8; ++kk) {
        short8 a;
        a[0] = (short)f2bf(lo[kk].x); a[1] = (short)f2bf(lo[kk].y);
        a[2] = (short)f2bf(lo[kk].z); a[3] = (short)f2bf(lo[kk].w);
        a[4] = (short)f2bf(hi[kk].x); a[5] = (short)f2bf(hi[kk].y);
        a[6] = (short)f2bf(hi[kk].z); a[7] = (short)f2bf(hi[kk].w);
        afrag[kk] = a;
    }

    const int t1 = t0 + 1;
    const bool have1 = t1 < NUM_TILES;
    if (have1) {
        const float* xrow = x + (size_t)(t1 * 16 + n16) * D_IN + quad * 8;
#pragma unroll
        for (int kk = 0; kk < 8; ++kk) {
            lo[kk] = *(const float4*)(xrow + kk * 32);
            hi[kk] = *(const float4*)(xrow + kk * 32 + 4);
        }
    }

    mfma_store_tile(afrag, wT, hiddenBf, t0 * 16, n16, quad);

    if (have1) {
#pragma unroll
        for (int kk = 0; kk < 8; ++kk) {
            short8 a;
            a[0] = (short)f2bf(lo[kk].x); a[1] = (short)f2bf(lo[kk].y);
            a[2] = (short)f2bf(lo[kk].z); a[3] = (short)f2bf(lo[kk].w);
            a[4] = (short)f2bf(hi[kk].x); a[5] = (short)f2bf(hi[kk].y);
            a[6] = (short)f2bf(hi[kk].z); a[7] = (short)f2bf(hi[kk].w);
            afrag[kk] = a;
        }
        mfma_store_tile(afrag, wT, hiddenBf, t1 * 16, n16, quad);
    }
}

// ---------------------------------------------------------------------------
// MFMA aggregation (round 7, unchanged). One wave per 16-node bucket.
// Per 64-edge group: two K=32 sub-chunks. H staged transposed in LDS
// (lane=dim), selector A-frag built from shfl'd records (adj hi/lo bf16,
// 2 MFMAs per B-frag). Zero-padded lanes contribute adj=0 -> no tail
// handling. No LDS RMW chain, no atomics, no barriers. LDS 40 KB.
// ---------------------------------------------------------------------------
__global__ __launch_bounds__(512) void agg_mfma_kernel(
    const unsigned short* __restrict__ hiddenBf,
    const int2* __restrict__ edges, const int* __restrict__ gCursor,
    const float* __restrict__ prelu_a, float* __restrict__ out)
{
    __shared__ unsigned short hT[8][64][40];   // per-wave [dim][edge], pitch 40

    const int t    = threadIdx.x;
    const int lane = t & 63;
    const int wid  = t >> 6;
    const int bucket = blockIdx.x * 8 + wid;
    if (bucket >= N_BKT) return;   // safe: no barriers in this kernel

    const int n16  = lane & 15;
    const int quad = lane >> 4;

    unsigned short (*H)[40] = hT[wid];

    f32x4 acc[4] = {{0.f,0.f,0.f,0.f},{0.f,0.f,0.f,0.f},
                    {0.f,0.f,0.f,0.f},{0.f,0.f,0.f,0.f}};

    const int base = bucket * BKT_CAP;
    int size = gCursor[bucket];
    if (size > BKT_CAP) size = BKT_CAP;

    for (int i0 = 0; i0 < size; i0 += 64) {
        int take = size - i0;
        if (take > 64) take = 64;
        int2 rec = make_int2(0, 0);
        if (lane < take) rec = edges[base + i0 + lane];

#pragma unroll
        for (int s = 0; s < 2; ++s) {
            // ---- stage 32 rows transposed: lane = dim, 16-deep gathers ----
#pragma unroll
            for (int g = 0; g < 2; ++g) {
                int cc[16]; unsigned short hh[16];
#pragma unroll
                for (int u = 0; u < 16; ++u)
                    cc[u] = __builtin_amdgcn_readlane(rec.x, s * 32 + g * 16 + u)
                            & 0x1FFFF;
#pragma unroll
                for (int u = 0; u < 16; ++u)
                    hh[u] = hiddenBf[(size_t)cc[u] * D_OUT + lane];
#pragma unroll
                for (int u = 0; u < 16; u += 4) {
                    u16x4 p;
                    p[0] = hh[u]; p[1] = hh[u + 1];
                    p[2] = hh[u + 2]; p[3] = hh[u + 3];
                    *(u16x4*)&H[lane][g * 16 + u] = p;
                }
            }

            // ---- selector A-fragments (hi/lo) ----
            short8 ahi, alo;
#pragma unroll
            for (int j = 0; j < 8; ++j) {
                int e  = s * 32 + quad * 8 + j;
                int rx = __shfl(rec.x, e);
                int ry = __shfl(rec.y, e);
                bool m = (((unsigned)rx >> 17) == (unsigned)n16);
                ahi[j] = m ? (short)((unsigned)ry >> 16) : (short)0;
                alo[j] = m ? (short)(ry & 0xFFFF)        : (short)0;
            }

            // ---- B-frags + MFMA ----
#pragma unroll
            for (int ct = 0; ct < 4; ++ct) {
                short8 b = *(const short8*)&H[ct * 16 + n16][quad * 8];
                acc[ct] = __builtin_amdgcn_mfma_f32_16x16x32_bf16(
                    ahi, b, acc[ct], 0, 0, 0);
                acc[ct] = __builtin_amdgcn_mfma_f32_16x16x32_bf16(
                    alo, b, acc[ct], 0, 0, 0);
            }
        }
    }

    // epilogue: PReLU + store. D layout: row(node)=quad*4+reg, col(dim)=n16.
    const float a = prelu_a[0];
    const int node0 = bucket * NODES_PER_BKT;
#pragma unroll
    for (int ct = 0; ct < 4; ++ct)
#pragma unroll
        for (int r = 0; r < 4; ++r) {
            float sv = acc[ct][r];
            out[(size_t)(node0 + quad * 4 + r) * D_OUT + ct * 16 + n16]
                = sv > 0.f ? sv : a * sv;
        }
}

// ---------------------------------------------------------------------------
extern "C" void kernel_launch(void* const* d_in, const int* in_sizes, int n_in,
                              void* d_out, int out_size, void* d_ws, size_t ws_size,
                              hipStream_t stream)
{
    const float* x       = (const float*)d_in[0];
    const float* w       = (const float*)d_in[1];
    const float* adj     = (const float*)d_in[2];
    const float* prelu_a = (const float*)d_in[3];
    const int*   row     = (const int*)d_in[4];
    const int*   col     = (const int*)d_in[5];
    float* out = (float*)d_out;

    // workspace layout (bytes)
    char* ws = (char*)d_ws;
    unsigned short* hiddenBf = (unsigned short*)(ws);        // 12,800,000
    int2*  edges    = (int2*)        (ws + 12800000);        // 12,800,000 (6250*256*8)
    int*   gCursor  = (int*)         (ws + 25600000);        //     25,000

    hipMemsetAsync(gCursor, 0, N_BKT * sizeof(int), stream);

    gemm_bin_kernel<<<GEMM_BLOCKS, 256, 0, stream>>>(
        x, w, hiddenBf, row, col, adj, gCursor, edges);

    agg_mfma_kernel<<<AGG_BLOCKS, 512, 0, stream>>>(
        hiddenBf, edges, gCursor, prelu_a, out);
}

// Round 9
// 249.463 us; speedup vs baseline: 1.0215x; 1.0215x over previous
//
#include <hip/hip_runtime.h>

#define N_NODES 100000
#define N_EDGES 1000000
#define D_IN    256
#define D_OUT   64

// Round 9 = Round 7 structure + gCursor padded to one counter per 128-B
// line. R8's direct-append experiment measured ~37ns per global
// atomicAdd-return on the PACKED 25-KB counter array (1M returns -> +24us
// vs R5's 357K) -> same-line serialization at the fabric atomic point is
// the binding cost of binning. Padding gives each counter its own line:
// ~137 RMWs/line, 6250 lines in parallel.
#define BKT_SHIFT   4
#define NODES_PER_BKT 16
#define N_BKT       6250
#define BKT_CAP     256            // mean 160, sigma ~12.6 -> +7.6 sigma
#define EPB         2048           // edges per binning block
#define BIN_BLOCKS  489            // ceil(1e6 / 2048)
#define GEMM_BLOCKS 782            // 3128 waves, 2 tiles/wave, 6250 tiles exact
#define NUM_TILES   6250           // 100000 / 16 exactly
#define AGG_BLOCKS  782            // 8 wave-buckets/block -> 6256 >= 6250
#define CUR_STRIDE  32             // ints: 128 B per counter line

typedef __attribute__((ext_vector_type(8))) short short8;
typedef __attribute__((ext_vector_type(4))) float f32x4;
typedef __attribute__((ext_vector_type(4))) unsigned short u16x4;

__device__ __forceinline__ unsigned short f2bf(float f) {
    unsigned int u = __float_as_uint(f);
    u = (u + 0x7fffu + ((u >> 16) & 1u)) >> 16;
    return (unsigned short)u;
}

// MFMA + store for one 16-row tile; B read from LDS per use (keeps VGPRs for
// the A-load pipeline). wT pad = 272 shorts (544 B = 8 banks offset/row ->
// 4-way b128 aliasing instead of 8-way at 264).
__device__ __forceinline__ void mfma_store_tile(
    const short8 afrag[8], const unsigned short wT[64][272],
    unsigned short* __restrict__ hiddenBf, int r0, int n16, int quad)
{
    f32x4 acc[4] = {{0.f,0.f,0.f,0.f},{0.f,0.f,0.f,0.f},
                    {0.f,0.f,0.f,0.f},{0.f,0.f,0.f,0.f}};
#pragma unroll
    for (int ct = 0; ct < 4; ++ct) {
#pragma unroll
        for (int kk = 0; kk < 8; ++kk) {
            short8 b = *(const short8*)&wT[ct * 16 + n16][kk * 32 + quad * 8];
            acc[ct] = __builtin_amdgcn_mfma_f32_16x16x32_bf16(
                afrag[kk], b, acc[ct], 0, 0, 0);
        }
    }
    // C/D layout: col = lane&15, row = quad*4 + reg  [m89-verified]
#pragma unroll
    for (int ct = 0; ct < 4; ++ct)
#pragma unroll
        for (int reg = 0; reg < 4; ++reg)
            hiddenBf[(size_t)(r0 + quad * 4 + reg) * D_OUT + ct * 16 + n16]
                = f2bf(acc[ct][reg]);
}

// ---------------------------------------------------------------------------
// GEMM kernel (unchanged from round 7). Launched first; block 0 zeroes the
// padded gCursor slots (stream order protects bin).
// ---------------------------------------------------------------------------
__global__ __launch_bounds__(256, 2) void gemm_kernel(
    const float* __restrict__ x, const float* __restrict__ w,
    unsigned short* __restrict__ hiddenBf, int* __restrict__ gCursor)
{
    const int t = threadIdx.x;

    if (blockIdx.x == 0) {
        for (int i = t; i < N_BKT; i += 256) gCursor[i * CUR_STRIDE] = 0;
    }

    __shared__ unsigned short wT[64][272];

    for (int i = 0; i < 64; ++i) {
        int idx = t + i * 256;
        int k = idx >> 6, n = idx & 63;
        wT[n][k] = f2bf(w[idx]);
    }
    __syncthreads();

    const int lane = t & 63;
    const int wid  = t >> 6;
    const int n16  = lane & 15;
    const int quad = lane >> 4;

    const int waveGid = blockIdx.x * 4 + wid;
    const int t0 = waveGid * 2;
    if (t0 >= NUM_TILES) return;

    float4 lo[8], hi[8];
    short8 afrag[8];

    // prologue: issue all 16 loads of tile t0
    {
        const float* xrow = x + (size_t)(t0 * 16 + n16) * D_IN + quad * 8;
#pragma unroll
        for (int kk = 0; kk < 8; ++kk) {
            lo[kk] = *(const float4*)(xrow + kk * 32);
            hi[kk] = *(const float4*)(xrow + kk * 32 + 4);
        }
    }
#pragma unroll
    for (int kk = 0; kk < 8; ++kk) {
        short8 a;
        a[0] = (short)f2bf(lo[kk].x); a[1] = (short)f2bf(lo[kk].y);
        a[2] = (short)f2bf(lo[kk].z); a[3] = (short)f2bf(lo[kk].w);
        a[4] = (short)f2bf(hi[kk].x); a[5] = (short)f2bf(hi[kk].y);
        a[6] = (short)f2bf(hi[kk].z); a[7] = (short)f2bf(hi[kk].w);
        afrag[kk] = a;
    }

    const int t1 = t0 + 1;
    const bool have1 = t1 < NUM_TILES;
    if (have1) {
        const float* xrow = x + (size_t)(t1 * 16 + n16) * D_IN + quad * 8;
#pragma unroll
        for (int kk = 0; kk < 8; ++kk) {
            lo[kk] = *(const float4*)(xrow + kk * 32);
            hi[kk] = *(const float4*)(xrow + kk * 32 + 4);
        }
    }

    mfma_store_tile(afrag, wT, hiddenBf, t0 * 16, n16, quad);

    if (have1) {
#pragma unroll
        for (int kk = 0; kk < 8; ++kk) {
            short8 a;
            a[0] = (short)f2bf(lo[kk].x); a[1] = (short)f2bf(lo[kk].y);
            a[2] = (short)f2bf(lo[kk].z); a[3] = (short)f2bf(lo[kk].w);
            a[4] = (short)f2bf(hi[kk].x); a[5] = (short)f2bf(hi[kk].y);
            a[6] = (short)f2bf(hi[kk].z); a[7] = (short)f2bf(hi[kk].w);
            afrag[kk] = a;
        }
        mfma_store_tile(afrag, wT, hiddenBf, t1 * 16, n16, quad);
    }
}

// ---------------------------------------------------------------------------
// Bin kernel (round 7 structure; round 9: padded gCursor). 489 blocks,
// 8 edges/thread, register-batched loads. Payload packs adj as
// (bf16_hi << 16) | bf16_lo; node-local in bits 17+.
// ---------------------------------------------------------------------------
__global__ __launch_bounds__(256, 2) void bin_kernel(
    const int* __restrict__ row, const int* __restrict__ col,
    const float* __restrict__ adj, int* __restrict__ gCursor,
    int2* __restrict__ edges)
{
    __shared__ int cnt[N_BKT];
    __shared__ int cbase[N_BKT];
    __shared__ int cur[N_BKT];

    const int t  = threadIdx.x;
    const int e0 = blockIdx.x * EPB;

    for (int i = t; i < N_BKT; i += 256) cnt[i] = 0;
    __syncthreads();

    int rreg[8];
#pragma unroll
    for (int u = 0; u < 8; ++u) {
        int e = e0 + t + u * 256;
        rreg[u] = (e < N_EDGES) ? row[e] : -1;
    }
#pragma unroll
    for (int u = 0; u < 8; ++u)
        if (rreg[u] >= 0) atomicAdd(&cnt[rreg[u] >> BKT_SHIFT], 1);
    __syncthreads();

    for (int i = t; i < N_BKT; i += 256) {
        int c = cnt[i];
        cbase[i] = c ? atomicAdd(&gCursor[i * CUR_STRIDE], c) : 0;
        cur[i] = 0;
    }
    __syncthreads();

    int cc[8]; float vv[8];
#pragma unroll
    for (int u = 0; u < 8; ++u) {
        int e = e0 + t + u * 256;
        if (rreg[u] >= 0) { cc[u] = col[e]; vv[u] = adj[e]; }
        else              { cc[u] = 0;      vv[u] = 0.f;    }
    }
#pragma unroll
    for (int u = 0; u < 8; ++u) {
        int r = rreg[u];
        if (r >= 0) {
            int b = r >> BKT_SHIFT;
            int off = cbase[b] + atomicAdd(&cur[b], 1);
            if (off < BKT_CAP) {  // capacity guard (never trips)
                unsigned hi = f2bf(vv[u]);
                float hif  = __uint_as_float(hi << 16);
                unsigned lo = f2bf(vv[u] - hif);
                edges[b * BKT_CAP + off] =
                    make_int2(((r & (NODES_PER_BKT - 1)) << 17) | cc[u],
                              (int)((hi << 16) | lo));
            }
        }
    }
}

// ---------------------------------------------------------------------------
// MFMA aggregation (round 7, unchanged except padded gCursor read). One wave
// per 16-node bucket; H staged transposed in LDS; selector A-frag from
// shfl'd records (adj hi/lo bf16, 2 MFMAs per B-frag). Zero-padded lanes
// contribute adj=0 -> no tail handling. No atomics, no barriers. LDS 40 KB.
// ---------------------------------------------------------------------------
__global__ __launch_bounds__(512) void agg_mfma_kernel(
    const unsigned short* __restrict__ hiddenBf,
    const int2* __restrict__ edges, const int* __restrict__ gCursor,
    const float* __restrict__ prelu_a, float* __restrict__ out)
{
    __shared__ unsigned short hT[8][64][40];   // per-wave [dim][edge], pitch 40

    const int t    = threadIdx.x;
    const int lane = t & 63;
    const int wid  = t >> 6;
    const int bucket = blockIdx.x * 8 + wid;
    if (bucket >= N_BKT) return;   // safe: no barriers in this kernel

    const int n16  = lane & 15;
    const int quad = lane >> 4;

    unsigned short (*H)[40] = hT[wid];

    f32x4 acc[4] = {{0.f,0.f,0.f,0.f},{0.f,0.f,0.f,0.f},
                    {0.f,0.f,0.f,0.f},{0.f,0.f,0.f,0.f}};

    const int base = bucket * BKT_CAP;
    int size = gCursor[bucket * CUR_STRIDE];
    if (size > BKT_CAP) size = BKT_CAP;

    for (int i0 = 0; i0 < size; i0 += 64) {
        int take = size - i0;
        if (take > 64) take = 64;
        int2 rec = make_int2(0, 0);
        if (lane < take) rec = edges[base + i0 + lane];

#pragma unroll
        for (int s = 0; s < 2; ++s) {
            // ---- stage 32 rows transposed: lane = dim, 16-deep gathers ----
#pragma unroll
            for (int g = 0; g < 2; ++g) {
                int cc[16]; unsigned short hh[16];
#pragma unroll
                for (int u = 0; u < 16; ++u)
                    cc[u] = __builtin_amdgcn_readlane(rec.x, s * 32 + g * 16 + u)
                            & 0x1FFFF;
#pragma unroll
                for (int u = 0; u < 16; ++u)
                    hh[u] = hiddenBf[(size_t)cc[u] * D_OUT + lane];
#pragma unroll
                for (int u = 0; u < 16; u += 4) {
                    u16x4 p;
                    p[0] = hh[u]; p[1] = hh[u + 1];
                    p[2] = hh[u + 2]; p[3] = hh[u + 3];
                    *(u16x4*)&H[lane][g * 16 + u] = p;
                }
            }

            // ---- selector A-fragments (hi/lo) ----
            short8 ahi, alo;
#pragma unroll
            for (int j = 0; j < 8; ++j) {
                int e  = s * 32 + quad * 8 + j;
                int rx = __shfl(rec.x, e);
                int ry = __shfl(rec.y, e);
                bool m = (((unsigned)rx >> 17) == (unsigned)n16);
                ahi[j] = m ? (short)((unsigned)ry >> 16) : (short)0;
                alo[j] = m ? (short)(ry & 0xFFFF)        : (short)0;
            }

            // ---- B-frags + MFMA ----
#pragma unroll
            for (int ct = 0; ct < 4; ++ct) {
                short8 b = *(const short8*)&H[ct * 16 + n16][quad * 8];
                acc[ct] = __builtin_amdgcn_mfma_f32_16x16x32_bf16(
                    ahi, b, acc[ct], 0, 0, 0);
                acc[ct] = __builtin_amdgcn_mfma_f32_16x16x32_bf16(
                    alo, b, acc[ct], 0, 0, 0);
            }
        }
    }

    // epilogue: PReLU + store. D layout: row(node)=quad*4+reg, col(dim)=n16.
    const float a = prelu_a[0];
    const int node0 = bucket * NODES_PER_BKT;
#pragma unroll
    for (int ct = 0; ct < 4; ++ct)
#pragma unroll
        for (int r = 0; r < 4; ++r) {
            float sv = acc[ct][r];
            out[(size_t)(node0 + quad * 4 + r) * D_OUT + ct * 16 + n16]
                = sv > 0.f ? sv : a * sv;
        }
}

// ---------------------------------------------------------------------------
extern "C" void kernel_launch(void* const* d_in, const int* in_sizes, int n_in,
                              void* d_out, int out_size, void* d_ws, size_t ws_size,
                              hipStream_t stream)
{
    const float* x       = (const float*)d_in[0];
    const float* w       = (const float*)d_in[1];
    const float* adj     = (const float*)d_in[2];
    const float* prelu_a = (const float*)d_in[3];
    const int*   row     = (const int*)d_in[4];
    const int*   col     = (const int*)d_in[5];
    float* out = (float*)d_out;

    // workspace layout (bytes)
    char* ws = (char*)d_ws;
    unsigned short* hiddenBf = (unsigned short*)(ws);        // 12,800,000
    int2*  edges    = (int2*)        (ws + 12800000);        // 12,800,000 (6250*256*8)
    int*   gCursor  = (int*)         (ws + 25600000);        //    800,000 (6250 x 128B)

    // no hipMemsetAsync: gemm block 0 zeroes gCursor (stream-ordered).
    gemm_kernel<<<GEMM_BLOCKS, 256, 0, stream>>>(x, w, hiddenBf, gCursor);

    bin_kernel<<<BIN_BLOCKS, 256, 0, stream>>>(row, col, adj, gCursor, edges);

    agg_mfma_kernel<<<AGG_BLOCKS, 512, 0, stream>>>(
        hiddenBf, edges, gCursor, prelu_a, out);
}

// Round 12
// 222.101 us; speedup vs baseline: 1.1473x; 1.1232x over previous
//
#include <hip/hip_runtime.h>

#define N_NODES 100000
#define N_EDGES 1000000
#define D_IN    256
#define D_OUT   64

// 16-node buckets, MFMA aggregation (round 7, verified numerics).
#define BKT_SHIFT   4
#define NODES_PER_BKT 16
#define N_BKT       6250
#define BKT_CAP     256            // mean 160, sigma ~12.6 -> +7.6 sigma

// Round 12 = Round 11 resubmitted (container infra failure, no data).
// R7 base + (a) bin re-fused into the gemm dispatch (R5-proven pattern:
// independent work, concurrent phases, one less gap) and (b) fat bin
// blocks: 123 x 8192 edges, 32/thread (R3-verified), cnt/cur merged ->
// 50 KB LDS union -> 3 blocks/CU. Global atomic-returns: 853K -> 562K;
// 6250-long LDS loops replicated 123x instead of 489x.
#define EPB         8192
#define BIN_BLOCKS  123            // ceil(1e6 / 8192)
#define GEMM_BLOCKS 782            // 3128 waves, 2 tiles/wave, 6250 tiles
#define NUM_TILES   6250           // 100000 / 16 exactly
#define AGG_BLOCKS  782            // 8 wave-buckets/block -> 6256 >= 6250

typedef __attribute__((ext_vector_type(8))) short short8;
typedef __attribute__((ext_vector_type(4))) float f32x4;
typedef __attribute__((ext_vector_type(4))) unsigned short u16x4;

__device__ __forceinline__ unsigned short f2bf(float f) {
    unsigned int u = __float_as_uint(f);
    u = (u + 0x7fffu + ((u >> 16) & 1u)) >> 16;
    return (unsigned short)u;
}

// MFMA + store for one 16-row tile; B read from LDS per use. wT pad = 272
// shorts (544 B = 8 banks offset/row -> 4-way b128 aliasing).
__device__ __forceinline__ void mfma_store_tile(
    const short8 afrag[8], const unsigned short wT[64][272],
    unsigned short* __restrict__ hiddenBf, int r0, int n16, int quad)
{
    f32x4 acc[4] = {{0.f,0.f,0.f,0.f},{0.f,0.f,0.f,0.f},
                    {0.f,0.f,0.f,0.f},{0.f,0.f,0.f,0.f}};
#pragma unroll
    for (int ct = 0; ct < 4; ++ct) {
#pragma unroll
        for (int kk = 0; kk < 8; ++kk) {
            short8 b = *(const short8*)&wT[ct * 16 + n16][kk * 32 + quad * 8];
            acc[ct] = __builtin_amdgcn_mfma_f32_16x16x32_bf16(
                afrag[kk], b, acc[ct], 0, 0, 0);
        }
    }
    // C/D layout: col = lane&15, row = quad*4 + reg  [m89-verified]
#pragma unroll
    for (int ct = 0; ct < 4; ++ct)
#pragma unroll
        for (int reg = 0; reg < 4; ++reg)
            hiddenBf[(size_t)(r0 + quad * 4 + reg) * D_OUT + ct * 16 + n16]
                = f2bf(acc[ct][reg]);
}

// ---------------------------------------------------------------------------
// Fused dispatch: blocks [0,123) bin; [123,905) gemm. LDS union = 50 KB
// (bin: cnt+cbase, cnt reused as cursor after pass 3) -> 3 blocks/CU.
// ---------------------------------------------------------------------------
__global__ __launch_bounds__(256, 2) void gemm_bin_kernel(
    const float* __restrict__ x, const float* __restrict__ w,
    unsigned short* __restrict__ hiddenBf,
    const int* __restrict__ row, const int* __restrict__ col,
    const float* __restrict__ adj, int* __restrict__ gCursor,
    int2* __restrict__ edges)
{
    __shared__ union {
        struct { int cnt[N_BKT]; int cbase[N_BKT]; } bin;   // 50,000 B
        unsigned short wT[64][272];                         // 34,816 B
    } smem;

    const int t = threadIdx.x;

    if (blockIdx.x < BIN_BLOCKS) {
        // ================= bin path =================
        int* cnt   = smem.bin.cnt;
        int* cbase = smem.bin.cbase;

        const int e0 = blockIdx.x * EPB;

        for (int i = t; i < N_BKT; i += 256) cnt[i] = 0;
        __syncthreads();

        // pass 1: 32 batched row loads (all in flight), kept for pass 4
        int rreg[32];
#pragma unroll
        for (int u = 0; u < 32; ++u) {
            int e = e0 + t + u * 256;
            rreg[u] = (e < N_EDGES) ? row[e] : -1;
        }
#pragma unroll
        for (int u = 0; u < 32; ++u)
            if (rreg[u] >= 0) atomicAdd(&cnt[rreg[u] >> BKT_SHIFT], 1);
        __syncthreads();

        // pass 3: reserve window; reset cnt for reuse as cursor
        for (int i = t; i < N_BKT; i += 256) {
            int c = cnt[i];
            cbase[i] = c ? atomicAdd(&gCursor[i], c) : 0;
            cnt[i] = 0;
        }
        __syncthreads();

        // pass 4: chunks of 8; col/adj batched; LDS cursor + scatter store
#pragma unroll
        for (int u0 = 0; u0 < 32; u0 += 8) {
            int cc[8]; float vv[8];
#pragma unroll
            for (int u = 0; u < 8; ++u) {
                int e = e0 + t + (u0 + u) * 256;
                if (rreg[u0 + u] >= 0) { cc[u] = col[e]; vv[u] = adj[e]; }
                else                   { cc[u] = 0;      vv[u] = 0.f;    }
            }
#pragma unroll
            for (int u = 0; u < 8; ++u) {
                int r = rreg[u0 + u];
                if (r >= 0) {
                    int b = r >> BKT_SHIFT;
                    int off = cbase[b] + atomicAdd(&cnt[b], 1);
                    if (off < BKT_CAP) {  // capacity guard (never trips)
                        unsigned hi = f2bf(vv[u]);
                        float hif   = __uint_as_float(hi << 16);
                        unsigned lo = f2bf(vv[u] - hif);
                        edges[b * BKT_CAP + off] =
                            make_int2(((r & (NODES_PER_BKT - 1)) << 17) | cc[u],
                                      (int)((hi << 16) | lo));
                    }
                }
            }
        }
        return;
    }

    // ================= gemm path (R7, verbatim) =================
    for (int i = 0; i < 64; ++i) {
        int idx = t + i * 256;
        int k = idx >> 6, n = idx & 63;
        smem.wT[n][k] = f2bf(w[idx]);
    }
    __syncthreads();

    const int lane = t & 63;
    const int wid  = t >> 6;
    const int n16  = lane & 15;
    const int quad = lane >> 4;

    const int waveGid = (blockIdx.x - BIN_BLOCKS) * 4 + wid;
    const int t0 = waveGid * 2;
    if (t0 >= NUM_TILES) return;

    float4 lo[8], hi[8];
    short8 afrag[8];

    {
        const float* xrow = x + (size_t)(t0 * 16 + n16) * D_IN + quad * 8;
#pragma unroll
        for (int kk = 0; kk < 8; ++kk) {
            lo[kk] = *(const float4*)(xrow + kk * 32);
            hi[kk] = *(const float4*)(xrow + kk * 32 + 4);
        }
    }
#pragma unroll
    for (int kk = 0; kk < 8; ++kk) {
        short8 a;
        a[0] = (short)f2bf(lo[kk].x); a[1] = (short)f2bf(lo[kk].y);
        a[2] = (short)f2bf(lo[kk].z); a[3] = (short)f2bf(lo[kk].w);
        a[4] = (short)f2bf(hi[kk].x); a[5] = (short)f2bf(hi[kk].y);
        a[6] = (short)f2bf(hi[kk].z); a[7] = (short)f2bf(hi[kk].w);
        afrag[kk] = a;
    }

    const int t1 = t0 + 1;
    const bool have1 = t1 < NUM_TILES;
    if (have1) {
        const float* xrow = x + (size_t)(t1 * 16 + n16) * D_IN + quad * 8;
#pragma unroll
        for (int kk = 0; kk < 8; ++kk) {
            lo[kk] = *(const float4*)(xrow + kk * 32);
            hi[kk] = *(const float4*)(xrow + kk * 32 + 4);
        }
    }

    mfma_store_tile(afrag, smem.wT, hiddenBf, t0 * 16, n16, quad);

    if (have1) {
#pragma unroll
        for (int kk = 0; kk < 8; ++kk) {
            short8 a;
            a[0] = (short)f2bf(lo[kk].x); a[1] = (short)f2bf(lo[kk].y);
            a[2] = (short)f2bf(lo[kk].z); a[3] = (short)f2bf(lo[kk].w);
            a[4] = (short)f2bf(hi[kk].x); a[5] = (short)f2bf(hi[kk].y);
            a[6] = (short)f2bf(hi[kk].z); a[7] = (short)f2bf(hi[kk].w);
            afrag[kk] = a;
        }
        mfma_store_tile(afrag, smem.wT, hiddenBf, t1 * 16, n16, quad);
    }
}

// ---------------------------------------------------------------------------
// MFMA aggregation (round 7, verbatim). One wave per 16-node bucket; H
// staged transposed in LDS; selector A-frag from shfl'd records (adj hi/lo
// bf16, 2 MFMAs per B-frag). Zero-padded lanes contribute adj=0. No
// atomics, no barriers. LDS 40 KB.
// ---------------------------------------------------------------------------
__global__ __launch_bounds__(512) void agg_mfma_kernel(
    const unsigned short* __restrict__ hiddenBf,
    const int2* __restrict__ edges, const int* __restrict__ gCursor,
    const float* __restrict__ prelu_a, float* __restrict__ out)
{
    __shared__ unsigned short hT[8][64][40];   // per-wave [dim][edge], pitch 40

    const int t    = threadIdx.x;
    const int lane = t & 63;
    const int wid  = t >> 6;
    const int bucket = blockIdx.x * 8 + wid;
    if (bucket >= N_BKT) return;   // safe: no barriers in this kernel

    const int n16  = lane & 15;
    const int quad = lane >> 4;

    unsigned short (*H)[40] = hT[wid];

    f32x4 acc[4] = {{0.f,0.f,0.f,0.f},{0.f,0.f,0.f,0.f},
                    {0.f,0.f,0.f,0.f},{0.f,0.f,0.f,0.f}};

    const int base = bucket * BKT_CAP;
    int size = gCursor[bucket];
    if (size > BKT_CAP) size = BKT_CAP;

    for (int i0 = 0; i0 < size; i0 += 64) {
        int take = size - i0;
        if (take > 64) take = 64;
        int2 rec = make_int2(0, 0);
        if (lane < take) rec = edges[base + i0 + lane];

#pragma unroll
        for (int s = 0; s < 2; ++s) {
            // stage 32 rows transposed: lane = dim, 16-deep gathers
#pragma unroll
            for (int g = 0; g < 2; ++g) {
                int cc[16]; unsigned short hh[16];
#pragma unroll
                for (int u = 0; u < 16; ++u)
                    cc[u] = __builtin_amdgcn_readlane(rec.x, s * 32 + g * 16 + u)
                            & 0x1FFFF;
#pragma unroll
                for (int u = 0; u < 16; ++u)
                    hh[u] = hiddenBf[(size_t)cc[u] * D_OUT + lane];
#pragma unroll
                for (int u = 0; u < 16; u += 4) {
                    u16x4 p;
                    p[0] = hh[u]; p[1] = hh[u + 1];
                    p[2] = hh[u + 2]; p[3] = hh[u + 3];
                    *(u16x4*)&H[lane][g * 16 + u] = p;
                }
            }

            // selector A-fragments (hi/lo)
            short8 ahi, alo;
#pragma unroll
            for (int j = 0; j < 8; ++j) {
                int e  = s * 32 + quad * 8 + j;
                int rx = __shfl(rec.x, e);
                int ry = __shfl(rec.y, e);
                bool m = (((unsigned)rx >> 17) == (unsigned)n16);
                ahi[j] = m ? (short)((unsigned)ry >> 16) : (short)0;
                alo[j] = m ? (short)(ry & 0xFFFF)        : (short)0;
            }

            // B-frags + MFMA
#pragma unroll
            for (int ct = 0; ct < 4; ++ct) {
                short8 b = *(const short8*)&H[ct * 16 + n16][quad * 8];
                acc[ct] = __builtin_amdgcn_mfma_f32_16x16x32_bf16(
                    ahi, b, acc[ct], 0, 0, 0);
                acc[ct] = __builtin_amdgcn_mfma_f32_16x16x32_bf16(
                    alo, b, acc[ct], 0, 0, 0);
            }
        }
    }

    // epilogue: PReLU + store. row(node)=quad*4+reg, col(dim)=n16.
    const float a = prelu_a[0];
    const int node0 = bucket * NODES_PER_BKT;
#pragma unroll
    for (int ct = 0; ct < 4; ++ct)
#pragma unroll
        for (int r = 0; r < 4; ++r) {
            float sv = acc[ct][r];
            out[(size_t)(node0 + quad * 4 + r) * D_OUT + ct * 16 + n16]
                = sv > 0.f ? sv : a * sv;
        }
}

// ---------------------------------------------------------------------------
extern "C" void kernel_launch(void* const* d_in, const int* in_sizes, int n_in,
                              void* d_out, int out_size, void* d_ws, size_t ws_size,
                              hipStream_t stream)
{
    const float* x       = (const float*)d_in[0];
    const float* w       = (const float*)d_in[1];
    const float* adj     = (const float*)d_in[2];
    const float* prelu_a = (const float*)d_in[3];
    const int*   row     = (const int*)d_in[4];
    const int*   col     = (const int*)d_in[5];
    float* out = (float*)d_out;

    // workspace layout (bytes)
    char* ws = (char*)d_ws;
    unsigned short* hiddenBf = (unsigned short*)(ws);        // 12,800,000
    int2*  edges    = (int2*)        (ws + 12800000);        // 12,800,000 (6250*256*8)
    int*   gCursor  = (int*)         (ws + 25600000);        //     25,000

    hipMemsetAsync(gCursor, 0, N_BKT * sizeof(int), stream);

    gemm_bin_kernel<<<BIN_BLOCKS + GEMM_BLOCKS, 256, 0, stream>>>(
        x, w, hiddenBf, row, col, adj, gCursor, edges);

    agg_mfma_kernel<<<AGG_BLOCKS, 512, 0, stream>>>(
        hiddenBf, edges, gCursor, prelu_a, out);
}